// Round 5
// baseline (575.901 us; speedup 1.0000x reference)
//
#include <hip/hip_runtime.h>
#include <cstdint>
#include <cstddef>

// Problem constants
#define BATCH 8
#define CIN   512
#define COUT  512
#define RES   64
#define HW    4096      // 64*64
#define WDIM  512

typedef short bf16x8 __attribute__((ext_vector_type(8)));
typedef float f32x4  __attribute__((ext_vector_type(4)));
typedef unsigned short ushort8 __attribute__((ext_vector_type(8)));

typedef const __attribute__((address_space(1))) void* gas_ptr;
typedef __attribute__((address_space(3))) void*       las_ptr;

__device__ __forceinline__ unsigned short f2bf(float f) {
    unsigned int u = __float_as_uint(f);
    u += 0x7fffu + ((u >> 16) & 1u);   // round-to-nearest-even
    return (unsigned short)(u >> 16);
}

// ---------------------------------------------------------------------------
// Kernel 1 (single fused prep, full parallelism):
//  blocks 0..4095 : ONE 64x64 modtrans tile each (b, ci_blk, hw_tile), with
//                   inline style for its 64 ci (redundant x64 per (b,ci_blk);
//                   aw is L2-resident, ~512 MB aggregate L2 reads ~= 15 us).
//                   xs[b][hw][ci] = bf16(x[b][ci][hw] * style[b][ci])
//  blocks 4096..4607: weight reorg wr[tap][co][ci] = bf16(weight[co][ci][tap]);
//                   block 4096 also zeroes the conv OOB zero-page.
// ---------------------------------------------------------------------------
__global__ __launch_bounds__(256) void prep_kernel(
    const float* __restrict__ x,  const float* __restrict__ w,
    const float* __restrict__ aw, const float* __restrict__ ab,
    const float* __restrict__ wt,
    unsigned short* __restrict__ xs, unsigned short* __restrict__ wr,
    unsigned short* __restrict__ zpage)
{
    __shared__ float sh[4608];   // tile[64][65]=4160 | partials[256] | style[64]
    const int bid = blockIdx.x;
    const int t   = threadIdx.x;

    if (bid < 4096) {
        const int b   = bid & 7;
        const int ci0 = ((bid >> 3) & 7) * 64;
        const int hw0 = (bid >> 6) * 64;

        float* tile     = sh;          // [64][65]
        float* partials = sh + 4160;   // [256]
        float* styleS   = sh + 4416;   // [64]

        // inline style: thread t -> (ci = t>>2, quarter q = t&3)
        {
            int cil = t >> 2, q = t & 3;
            const f32x4* arow = (const f32x4*)(aw + (size_t)(ci0 + cil) * WDIM + q * 128);
            const f32x4* wrow = (const f32x4*)(w + (size_t)b * WDIM + q * 128);
            float s = 0.f;
#pragma unroll
            for (int i = 0; i < 32; ++i) {
                f32x4 a = arow[i], ww = wrow[i];
                s += a.x * ww.x + a.y * ww.y + a.z * ww.z + a.w * ww.w;
            }
            partials[t] = s;
        }
        __syncthreads();
        if (t < 64)
            styleS[t] = partials[t * 4] + partials[t * 4 + 1] + partials[t * 4 + 2]
                      + partials[t * 4 + 3] + ab[ci0 + t];
        __syncthreads();

        int sub = t >> 6, lane = t & 63;
#pragma unroll
        for (int r = 0; r < 16; ++r) {
            int ci = r * 4 + sub;
            tile[ci * 65 + lane] =
                x[((size_t)(b * CIN + ci0 + ci)) * HW + hw0 + lane] * styleS[ci];
        }
        __syncthreads();
        int ci8 = (t & 7) * 8;
#pragma unroll
        for (int r = 0; r < 2; ++r) {
            int hw = r * 32 + (t >> 3);
            ushort8 v;
#pragma unroll
            for (int j = 0; j < 8; ++j) v[j] = f2bf(tile[(ci8 + j) * 65 + hw]);
            *(ushort8*)&xs[((size_t)b * HW + hw0 + hw) * CIN + ci0 + ci8] = v;
        }
    } else {
        if (bid == 4096 && t < 128) zpage[t] = 0;
        int co = bid - 4096;
#pragma unroll
        for (int r = 0; r < 18; ++r) sh[r * 256 + t] = wt[(size_t)co * 4608 + r * 256 + t];
        __syncthreads();
#pragma unroll
        for (int r = 0; r < 18; ++r) {
            int idx = r * 256 + t;
            int tap = idx >> 9, ci = idx & 511;
            wr[(size_t)tap * (COUT * CIN) + co * CIN + ci] = f2bf(sh[ci * 9 + tap]);
        }
    }
}

// ---------------------------------------------------------------------------
// Kernel 2: implicit-GEMM conv, B-only LDS, A direct from global.
// C-tile 128(co) x 256(hw = 4 image rows), 512 threads = 8 waves, each wave a
// 64x64 quadrant. Outer kh (3), inner ci-chunk of 64 (8 chunks): 24 barrier
// pairs, 288 MFMA per wave per pair-triple... 96 MFMA per barrier pair.
// A fragments are loaded straight from wr (K-contiguous 16B per lane); the 4
// waves sharing wm read identical addresses -> L1 broadcast. B staged once
// per (kh,ch) into zero-padded Bs[4][66][64] and reused by all 3 kw via a
// column shift. XOR swizzle: 16B chunk j of row r at slot j^(r&7) (rows are
// exactly 128 B): fragment reads spread 2-way over banks = free.
// LDS 33 KB; grid 512 -> 2 blocks/CU, 16 waves/CU. bid%8 = batch so
// co-siblings share an XCD's L2.
// ---------------------------------------------------------------------------
__global__ __launch_bounds__(512, 4) void conv_kernel(
    const unsigned short* __restrict__ xs,   // [8][4096][512] bf16
    const unsigned short* __restrict__ wr,   // [9][512][512]  bf16
    const float* __restrict__ bias,
    const unsigned short* __restrict__ zpage,
    float* __restrict__ y)                   // [8][512][4096] f32
{
    __shared__ __align__(16) unsigned short Bs[4 * 66 * 64];   // 33 KB

    const int t   = threadIdx.x;
    const int bid = blockIdx.x;
    const int b   = bid & 7;
    const int h0  = ((bid >> 3) & 15) * 4;
    const int co0 = (bid >> 7) * 128;

    const int lane = t & 63;
    const int wv   = t >> 6;
    const int wm   = (wv & 1) * 64;
    const int wn   = (wv >> 1) * 64;      // 0,64,128,192
    const int r16  = lane & 15;
    const int quad = lane >> 4;

    // zero the pad columns (wcol=0 and wcol=65) of all 4 staged rows
    {
        int s = t >> 7, rest = t & 127;
        int col = (rest < 64) ? 0 : 65;
        Bs[(s * 66 + col) * 64 + (rest & 63)] = 0;
    }

    // A-fragment per-lane element offsets (ci-contiguous 16B), mi = 0..3
    int avoff[4];
#pragma unroll
    for (int mi = 0; mi < 4; ++mi)
        avoff[mi] = (co0 + wm + mi * 16 + r16) * CIN + quad * 8;

    f32x4 acc[4][4];
#pragma unroll
    for (int mi = 0; mi < 4; ++mi)
#pragma unroll
        for (int ni = 0; ni < 4; ++ni)
            acc[mi][ni] = (f32x4){0.f, 0.f, 0.f, 0.f};

    for (int kh = 0; kh < 3; ++kh) {
        // B staging pointers: 4 x 16B per thread; load L covers staged row s=L
        // (input row h0+kh-1+L), 64 w-cols x 8 chunks. Source chunk is
        // swizzle-permuted; LDS dest stays base + lane*16.
        const unsigned short* pB[4];
        int sB[4];
#pragma unroll
        for (int L = 0; L < 4; ++L) {
            int wc = t >> 3, c = t & 7;
            int rowp = L * 66 + 1 + wc;
            int csrc = c ^ (rowp & 7);
            int hp = h0 + kh - 1 + L;
            bool ok = (unsigned)hp < 64u;
            pB[L] = ok ? xs + ((size_t)b * HW + hp * 64 + wc) * CIN + csrc * 8 : zpage;
            sB[L] = ok ? 64 : 0;
        }

        for (int ch = 0; ch < 8; ++ch) {
#pragma unroll
            for (int L = 0; L < 4; ++L) {
                __builtin_amdgcn_global_load_lds((gas_ptr)pB[L],
                    (las_ptr)&Bs[(L * 66 + 1) * 64 + t * 8], 16, 0, 0);
                pB[L] += sB[L];
            }
            __syncthreads();
#pragma unroll
            for (int kw = 0; kw < 3; ++kw) {
                const size_t tapoff = (size_t)(kh * 3 + kw) * (COUT * CIN) + ch * 64;
#pragma unroll
                for (int ksub = 0; ksub < 2; ++ksub) {
                    bf16x8 af[4], bfv[4];
#pragma unroll
                    for (int mi = 0; mi < 4; ++mi)
                        af[mi] = *(const bf16x8*)&wr[tapoff + avoff[mi] + ksub * 32];
#pragma unroll
                    for (int ni = 0; ni < 4; ++ni) {
                        int n = wn + ni * 16 + r16;
                        int dh = n >> 6, wc = n & 63;
                        int rowp = dh * 66 + wc + kw;
                        int cph = (ksub * 4 + quad) ^ (rowp & 7);
                        bfv[ni] = *(const bf16x8*)&Bs[rowp * 64 + cph * 8];
                    }
#pragma unroll
                    for (int mi = 0; mi < 4; ++mi)
#pragma unroll
                        for (int ni = 0; ni < 4; ++ni)
                            acc[mi][ni] = __builtin_amdgcn_mfma_f32_16x16x32_bf16(
                                af[mi], bfv[ni], acc[mi][ni], 0, 0, 0);
                }
            }
            __syncthreads();
        }
    }

    // Epilogue: C/D layout col(n)=lane&15, row(m)=quad*4+reg
#pragma unroll
    for (int mi = 0; mi < 4; ++mi) {
#pragma unroll
        for (int r = 0; r < 4; ++r) {
            int m = co0 + wm + mi * 16 + quad * 4 + r;
            float bv = bias[m];
            size_t base = ((size_t)b * COUT + m) * HW + h0 * 64;
#pragma unroll
            for (int ni = 0; ni < 4; ++ni) {
                int n = wn + ni * 16 + r16;
                y[base + n] = acc[mi][ni][r] + bv;
            }
        }
    }
}

// ---------------------------------------------------------------------------
extern "C" void kernel_launch(void* const* d_in, const int* in_sizes, int n_in,
                              void* d_out, int out_size, void* d_ws, size_t ws_size,
                              hipStream_t stream)
{
    (void)in_sizes; (void)n_in; (void)out_size; (void)ws_size;
    const float* x    = (const float*)d_in[0];  // [8,512,64,64]
    const float* w    = (const float*)d_in[1];  // [8,512]
    const float* wt   = (const float*)d_in[2];  // [512,512,3,3]
    const float* bias = (const float*)d_in[3];  // [512]
    const float* aw   = (const float*)d_in[4];  // [512,512]
    const float* ab   = (const float*)d_in[5];  // [512]
    float* y = (float*)d_out;                   // [8,512,64,64]

    char* ws = (char*)d_ws;
    unsigned short* zpage = (unsigned short*)(ws + 16384);       // 256 B
    unsigned short* wr    = (unsigned short*)(ws + 32768);       // 4.5 MB
    unsigned short* xs    = (unsigned short*)(ws + 4751360);     // 32 MB

    prep_kernel<<<4608, 256, 0, stream>>>(x, w, aw, ab, wt, xs, wr, zpage);
    conv_kernel<<<512, 512, 0, stream>>>(xs, wr, bias, zpage, y);
}